// Round 2
// baseline (921.964 us; speedup 1.0000x reference)
//
#include <hip/hip_runtime.h>

typedef __bf16 bf16_t;
typedef __attribute__((ext_vector_type(8))) __bf16 bf16x8;
typedef __attribute__((ext_vector_type(4))) float f32x4;

#define NB 16
#define NC 768
#define NT 1025
#define TP 1056
#define NH 12
#define DH 64
#define QK_SCALE 0.03608439182435161f  /* 1/sqrt(768) */

// ---------------- QKV depthwise conv + BN ----------------
// One thread per (b, pixel, channel). Writes Q (pre-scaled), K, V as bf16
// in [b*12+h][t][64] layout (t = 1+pixel).
__global__ __launch_bounds__(256) void qkv_conv(
    const float* __restrict__ x,
    const float* __restrict__ wq, const float* __restrict__ gq, const float* __restrict__ bq,
    const float* __restrict__ mq, const float* __restrict__ vq,
    const float* __restrict__ wk, const float* __restrict__ gk, const float* __restrict__ bk,
    const float* __restrict__ mk, const float* __restrict__ vk,
    const float* __restrict__ wv, const float* __restrict__ gv, const float* __restrict__ bv,
    const float* __restrict__ mv, const float* __restrict__ vv,
    bf16_t* __restrict__ Q, bf16_t* __restrict__ K, bf16_t* __restrict__ V)
{
    int idx = blockIdx.x * 256 + threadIdx.x;         // < 16*1024*768
    int c = idx % NC;
    int p = (idx / NC) & 1023;
    int b = idx / (NC * 1024);
    int y = p >> 5, xp = p & 31;
    const float* xb = x + ((size_t)b * NT + 1) * NC;  // body start

    float aq = 0.f, ak = 0.f, av = 0.f;
#pragma unroll
    for (int dy = -1; dy <= 1; ++dy) {
#pragma unroll
        for (int dx = -1; dx <= 1; ++dx) {
            int ny = y + dy, nx = xp + dx;
            float xv = 0.f;
            if (ny >= 0 && ny < 32 && nx >= 0 && nx < 32)
                xv = xb[(ny * 32 + nx) * NC + c];
            int wi = c * 9 + (dy + 1) * 3 + (dx + 1);
            aq += xv * wq[wi];
            ak += xv * wk[wi];
            av += xv * wv[wi];
        }
    }
    float sq = gq[c] * rsqrtf(vq[c] + 1e-5f);
    float sk = gk[c] * rsqrtf(vk[c] + 1e-5f);
    float sv = gv[c] * rsqrtf(vv[c] + 1e-5f);
    float oq = (aq * sq + (bq[c] - mq[c] * sq)) * QK_SCALE;
    float ok = ak * sk + (bk[c] - mk[c] * sk);
    float ov = av * sv + (bv[c] - mv[c] * sv);

    int h = c >> 6, dk = c & 63;
    size_t base = ((size_t)(b * NH + h) * TP + (1 + p)) * DH + dk;
    Q[base] = (bf16_t)oq;
    K[base] = (bf16_t)ok;
    V[base] = (bf16_t)ov;
}

// cls token row (t=0) passes through unchanged (Q gets the scale).
__global__ __launch_bounds__(256) void cls_fill(
    const float* __restrict__ x, bf16_t* __restrict__ Q, bf16_t* __restrict__ K, bf16_t* __restrict__ V)
{
    int idx = blockIdx.x * 256 + threadIdx.x;  // < 16*768
    int c = idx % NC;
    int b = idx / NC;
    float xv = x[(size_t)b * NT * NC + c];
    int h = c >> 6, dk = c & 63;
    size_t base = ((size_t)(b * NH + h) * TP + 0) * DH + dk;
    Q[base] = (bf16_t)(xv * QK_SCALE);
    K[base] = (bf16_t)xv;
    V[base] = (bf16_t)xv;
}

// ---------------- V transpose: [bh][t][64] -> [bh][64][t] ----------------
__global__ __launch_bounds__(256) void transpose_v(
    const bf16_t* __restrict__ V, bf16_t* __restrict__ Vt)
{
    __shared__ bf16_t tile[64][65];
    int bh = blockIdx.y;
    int t0 = blockIdx.x * 64;
    for (int i = threadIdx.x; i < 64 * 64; i += 256) {
        int tt = i >> 6, dk = i & 63;
        int t = t0 + tt;
        tile[tt][dk] = (t < TP) ? V[((size_t)bh * TP + t) * DH + dk] : (bf16_t)0.f;
    }
    __syncthreads();
    for (int i = threadIdx.x; i < 64 * 64; i += 256) {
        int dk = i >> 6, tt = i & 63;
        int t = t0 + tt;
        if (t < TP) Vt[((size_t)bh * DH + dk) * TP + t] = tile[tt][dk];
    }
}

// ---------------- flash attention: 1 wave = 16 Q rows of one (b,h) ----------------
__global__ __launch_bounds__(64) void attn_kernel(
    const bf16_t* __restrict__ Q, const bf16_t* __restrict__ K,
    const bf16_t* __restrict__ Vt, bf16_t* __restrict__ Oa)
{
    int wid = blockIdx.x;          // 192*66
    int qt = wid % 66;
    int bh = wid / 66;
    int b = bh / NH, h = bh % NH;
    int lane = threadIdx.x;
    int cl = lane & 15;            // col within 16-tile
    int gr = lane >> 4;            // group 0..3

    const bf16_t* Qb = Q + ((size_t)bh * TP + qt * 16) * DH;
    const bf16_t* Kb = K + (size_t)bh * TP * DH;
    const bf16_t* Vb = Vt + (size_t)bh * DH * TP;

    // Q fragments for 2 k-steps (K-dim = 64)
    bf16x8 qf0 = *(const bf16x8*)(Qb + cl * DH + gr * 8);
    bf16x8 qf1 = *(const bf16x8*)(Qb + cl * DH + 32 + gr * 8);

    f32x4 o0 = {0.f, 0.f, 0.f, 0.f}, o1 = o0, o2 = o0, o3 = o0;
    float mrow[4] = {-1e30f, -1e30f, -1e30f, -1e30f};
    float lrow[4] = {0.f, 0.f, 0.f, 0.f};

    __shared__ alignas(16) bf16_t pl[16][32];

    for (int kt = 0; kt < 33; ++kt) {
        int t0 = kt * 32;
        f32x4 s0 = {0.f, 0.f, 0.f, 0.f}, s1 = s0;
        const bf16_t* K0 = Kb + (size_t)(t0 + cl) * DH;
        bf16x8 kf;
        kf = *(const bf16x8*)(K0 + gr * 8);
        s0 = __builtin_amdgcn_mfma_f32_16x16x32_bf16(qf0, kf, s0, 0, 0, 0);
        kf = *(const bf16x8*)(K0 + 32 + gr * 8);
        s0 = __builtin_amdgcn_mfma_f32_16x16x32_bf16(qf1, kf, s0, 0, 0, 0);
        kf = *(const bf16x8*)(K0 + 16 * DH + gr * 8);
        s1 = __builtin_amdgcn_mfma_f32_16x16x32_bf16(qf0, kf, s1, 0, 0, 0);
        kf = *(const bf16x8*)(K0 + 16 * DH + 32 + gr * 8);
        s1 = __builtin_amdgcn_mfma_f32_16x16x32_bf16(qf1, kf, s1, 0, 0, 0);

        bool msk0 = (t0 + cl) >= NT;        // mask padded key columns
        bool msk1 = (t0 + 16 + cl) >= NT;
#pragma unroll
        for (int j = 0; j < 4; ++j) {
            float a = msk0 ? -1e30f : s0[j];
            float bb = msk1 ? -1e30f : s1[j];
            float mx = fmaxf(a, bb);
            mx = fmaxf(mx, __shfl_xor(mx, 1));
            mx = fmaxf(mx, __shfl_xor(mx, 2));
            mx = fmaxf(mx, __shfl_xor(mx, 4));
            mx = fmaxf(mx, __shfl_xor(mx, 8));
            float mn = fmaxf(mrow[j], mx);
            float alpha = __expf(mrow[j] - mn);
            mrow[j] = mn;
            float p0 = __expf(a - mn);
            float p1 = __expf(bb - mn);
            s0[j] = p0;
            s1[j] = p1;
            float rs = p0 + p1;
            rs += __shfl_xor(rs, 1);
            rs += __shfl_xor(rs, 2);
            rs += __shfl_xor(rs, 4);
            rs += __shfl_xor(rs, 8);
            lrow[j] = lrow[j] * alpha + rs;
            o0[j] *= alpha; o1[j] *= alpha; o2[j] *= alpha; o3[j] *= alpha;
        }
        // P tile (16x32) through LDS to get A-fragment layout
#pragma unroll
        for (int j = 0; j < 4; ++j) {
            pl[gr * 4 + j][cl] = (bf16_t)s0[j];
            pl[gr * 4 + j][16 + cl] = (bf16_t)s1[j];
        }
        __syncthreads();
        bf16x8 pa = *(const bf16x8*)(&pl[cl][gr * 8]);
        const bf16_t* V0 = Vb + t0 + gr * 8;
        bf16x8 vf;
        vf = *(const bf16x8*)(V0 + (size_t)(0 * 16 + cl) * TP);
        o0 = __builtin_amdgcn_mfma_f32_16x16x32_bf16(pa, vf, o0, 0, 0, 0);
        vf = *(const bf16x8*)(V0 + (size_t)(1 * 16 + cl) * TP);
        o1 = __builtin_amdgcn_mfma_f32_16x16x32_bf16(pa, vf, o1, 0, 0, 0);
        vf = *(const bf16x8*)(V0 + (size_t)(2 * 16 + cl) * TP);
        o2 = __builtin_amdgcn_mfma_f32_16x16x32_bf16(pa, vf, o2, 0, 0, 0);
        vf = *(const bf16x8*)(V0 + (size_t)(3 * 16 + cl) * TP);
        o3 = __builtin_amdgcn_mfma_f32_16x16x32_bf16(pa, vf, o3, 0, 0, 0);
        __syncthreads();
    }

    int tr0 = qt * 16;
#pragma unroll
    for (int j = 0; j < 4; ++j) {
        int t = tr0 + gr * 4 + j;
        if (t < NT) {
            float inv = 1.0f / lrow[j];
            size_t row = ((size_t)b * NT + t) * NC + h * DH;
            Oa[row + 0 * 16 + cl] = (bf16_t)(o0[j] * inv);
            Oa[row + 1 * 16 + cl] = (bf16_t)(o1[j] * inv);
            Oa[row + 2 * 16 + cl] = (bf16_t)(o2[j] * inv);
            Oa[row + 3 * 16 + cl] = (bf16_t)(o3[j] * inv);
        }
    }
}

// ---------------- W -> bf16 ----------------
__global__ __launch_bounds__(256) void conv_w(const float* __restrict__ W, bf16_t* __restrict__ Wb)
{
    int i = blockIdx.x * 256 + threadIdx.x;
    if (i < NC * NC) Wb[i] = (bf16_t)W[i];
}

// ---------------- projection GEMM: out[n][j] = sum_c Oa[n][c]*W[j][c] + bias[j] ----------------
__global__ __launch_bounds__(64) void proj_gemm(
    const bf16_t* __restrict__ Oa, const bf16_t* __restrict__ Wb,
    const float* __restrict__ bias, float* __restrict__ out)
{
    int wid = blockIdx.x;          // 1025 * 12
    int nt = wid % 12;             // 64-col tile
    int mt = wid / 12;             // 16-row tile
    int lane = threadIdx.x;
    int cl = lane & 15, gr = lane >> 4;

    const bf16_t* A = Oa + ((size_t)mt * 16 + cl) * NC + gr * 8;
    const bf16_t* Bp = Wb + ((size_t)(nt * 64 + cl)) * NC + gr * 8;
    f32x4 a0 = {0.f, 0.f, 0.f, 0.f}, a1 = a0, a2 = a0, a3 = a0;
#pragma unroll 4
    for (int ks = 0; ks < 24; ++ks) {
        bf16x8 af = *(const bf16x8*)(A + ks * 32);
        bf16x8 b0 = *(const bf16x8*)(Bp + 0 * 16 * NC + ks * 32);
        bf16x8 b1 = *(const bf16x8*)(Bp + 1 * 16 * NC + ks * 32);
        bf16x8 b2 = *(const bf16x8*)(Bp + 2 * 16 * NC + ks * 32);
        bf16x8 b3 = *(const bf16x8*)(Bp + 3 * 16 * NC + ks * 32);
        a0 = __builtin_amdgcn_mfma_f32_16x16x32_bf16(af, b0, a0, 0, 0, 0);
        a1 = __builtin_amdgcn_mfma_f32_16x16x32_bf16(af, b1, a1, 0, 0, 0);
        a2 = __builtin_amdgcn_mfma_f32_16x16x32_bf16(af, b2, a2, 0, 0, 0);
        a3 = __builtin_amdgcn_mfma_f32_16x16x32_bf16(af, b3, a3, 0, 0, 0);
    }
#pragma unroll
    for (int j = 0; j < 4; ++j) {
        int col = nt * 64 + j * 16 + cl;
        float bv = bias[col];
        f32x4 acc = (j == 0) ? a0 : (j == 1) ? a1 : (j == 2) ? a2 : a3;
#pragma unroll
        for (int jj = 0; jj < 4; ++jj) {
            int r = mt * 16 + gr * 4 + jj;
            out[(size_t)r * NC + col] = acc[jj] + bv;
        }
    }
}

extern "C" void kernel_launch(void* const* d_in, const int* in_sizes, int n_in,
                              void* d_out, int out_size, void* d_ws, size_t ws_size,
                              hipStream_t stream)
{
    const float* x = (const float*)d_in[0];
    // d_in[1]=h, d_in[2]=w (ints, fixed 32)
    const float* wq = (const float*)d_in[3];
    const float* gq = (const float*)d_in[4];
    const float* bq = (const float*)d_in[5];
    const float* mq = (const float*)d_in[6];
    const float* vq = (const float*)d_in[7];
    const float* wk = (const float*)d_in[8];
    const float* gk = (const float*)d_in[9];
    const float* bk = (const float*)d_in[10];
    const float* mk = (const float*)d_in[11];
    const float* vk = (const float*)d_in[12];
    const float* wv = (const float*)d_in[13];
    const float* gv = (const float*)d_in[14];
    const float* bv = (const float*)d_in[15];
    const float* mv = (const float*)d_in[16];
    const float* vv = (const float*)d_in[17];
    const float* pw = (const float*)d_in[18];
    const float* pb = (const float*)d_in[19];
    float* out = (float*)d_out;

    const size_t QKV_ELEMS = (size_t)NB * NH * TP * DH;   // 12,976,128
    bf16_t* ws = (bf16_t*)d_ws;
    bf16_t* Q  = ws;
    bf16_t* K  = ws + QKV_ELEMS;
    bf16_t* V  = ws + 2 * QKV_ELEMS;
    bf16_t* Vt = ws + 3 * QKV_ELEMS;
    bf16_t* Oa = ws + 4 * QKV_ELEMS;                      // 16400*768 bf16
    bf16_t* Wb = Oa + (size_t)NB * NT * NC;

    conv_w<<<(NC * NC + 255) / 256, 256, 0, stream>>>(pw, Wb);
    qkv_conv<<<(NB * 1024 * NC) / 256, 256, 0, stream>>>(
        x, wq, gq, bq, mq, vq, wk, gk, bk, mk, vk, wv, gv, bv, mv, vv, Q, K, V);
    cls_fill<<<(NB * NC) / 256, 256, 0, stream>>>(x, Q, K, V);
    transpose_v<<<dim3(17, NB * NH), 256, 0, stream>>>(V, Vt);
    attn_kernel<<<NB * NH * 66, 64, 0, stream>>>(Q, K, Vt, Oa);
    proj_gemm<<<1025 * 12, 64, 0, stream>>>(Oa, Wb, pb, out);
}

// Round 3
// 649.437 us; speedup vs baseline: 1.4196x; 1.4196x over previous
//
#include <hip/hip_runtime.h>

typedef __bf16 bf16_t;
typedef __attribute__((ext_vector_type(8))) __bf16 bf16x8;
typedef __attribute__((ext_vector_type(4))) float f32x4;

#define NB 16
#define NC 768
#define NT 1025
#define TP 1056
#define NH 12
#define DH 64
#define QK_SCALE 0.03608439182435161f  /* 1/sqrt(768) */

// ---------------- QKV depthwise conv + BN (register-blocked) ----------------
// grid (8 y-strips, 3 c-chunks, 16 b), block 256. Each thread owns ONE channel
// and computes a 4-row x 32-col strip. Weights (9 per conv) + BN constants are
// loaded once per thread into registers (the old per-pixel stride-36B weight
// gathers were ~250us of serialized cache-line requests). Rolling 6-row x
// 3-col register window: 6 coalesced x-loads per x-step for 12 outputs.
__global__ __launch_bounds__(256) void qkv_conv(
    const float* __restrict__ x,
    const float* __restrict__ wq, const float* __restrict__ gq, const float* __restrict__ bq,
    const float* __restrict__ mq, const float* __restrict__ vq,
    const float* __restrict__ wk, const float* __restrict__ gk, const float* __restrict__ bk,
    const float* __restrict__ mk, const float* __restrict__ vk,
    const float* __restrict__ wv, const float* __restrict__ gv, const float* __restrict__ bv,
    const float* __restrict__ mv, const float* __restrict__ vv,
    bf16_t* __restrict__ Q, bf16_t* __restrict__ K, bf16_t* __restrict__ V)
{
    const int tid = threadIdx.x;
    const int c  = blockIdx.y * 256 + tid;
    const int y0 = blockIdx.x * 4;
    const int b  = blockIdx.z;

    const float* xb = x + ((size_t)b * NT + 1) * NC + c;   // body start, this channel

    float WQ[9], WK[9], WV[9];
#pragma unroll
    for (int k = 0; k < 9; ++k) {
        WQ[k] = wq[c * 9 + k];
        WK[k] = wk[c * 9 + k];
        WV[k] = wv[c * 9 + k];
    }
    float sq = gq[c] * rsqrtf(vq[c] + 1e-5f);
    float tq = (bq[c] - mq[c] * sq) * QK_SCALE; sq *= QK_SCALE;
    float sk = gk[c] * rsqrtf(vk[c] + 1e-5f);
    float tk = bk[c] - mk[c] * sk;
    float sv = gv[c] * rsqrtf(vv[c] + 1e-5f);
    float tv = bv[c] - mv[c] * sv;

    const int h = c >> 6, dk = c & 63;
    // output base for t = 1 + (y0*32 + xo)
    bf16_t* Qo = Q + ((size_t)(b * NH + h) * TP + 1 + y0 * 32) * DH + dk;
    bf16_t* Ko = K + ((size_t)(b * NH + h) * TP + 1 + y0 * 32) * DH + dk;
    bf16_t* Vo = V + ((size_t)(b * NH + h) * TP + 1 + y0 * 32) * DH + dk;

    // rolling window: rows y0-1 .. y0+4, cols {x-1, x, x+1}
    float win[6][3];
#pragma unroll
    for (int r = 0; r < 6; ++r) {
        int yy = y0 - 1 + r;
        win[r][0] = 0.f;                                   // x = -1
        win[r][1] = (yy >= 0 && yy < 32) ? xb[(size_t)(yy * 32) * NC] : 0.f;  // x = 0
    }

#pragma unroll 4
    for (int xo = 0; xo < 32; ++xo) {
        // load column xo+1 (zeros at xo==31)
#pragma unroll
        for (int r = 0; r < 6; ++r) {
            int yy = y0 - 1 + r;
            win[r][2] = (xo < 31 && yy >= 0 && yy < 32)
                        ? xb[(size_t)(yy * 32 + xo + 1) * NC] : 0.f;
            // compute output rows that have their full 3x3 once all 3 cols present
        }
#pragma unroll
        for (int r = 0; r < 4; ++r) {                      // output row y0 + r
            float aq = 0.f, ak = 0.f, av = 0.f;
#pragma unroll
            for (int dy = 0; dy < 3; ++dy) {
#pragma unroll
                for (int dx = 0; dx < 3; ++dx) {
                    float xv = win[r + dy][dx];
                    aq += xv * WQ[dy * 3 + dx];
                    ak += xv * WK[dy * 3 + dx];
                    av += xv * WV[dy * 3 + dx];
                }
            }
            size_t o = ((size_t)(r * 32 + xo)) * DH;
            Qo[o] = (bf16_t)(aq * sq + tq);
            Ko[o] = (bf16_t)(ak * sk + tk);
            Vo[o] = (bf16_t)(av * sv + tv);
        }
        // shift window left
#pragma unroll
        for (int r = 0; r < 6; ++r) {
            win[r][0] = win[r][1];
            win[r][1] = win[r][2];
        }
    }
}

// cls token row (t=0) passes through unchanged (Q gets the scale).
__global__ __launch_bounds__(256) void cls_fill(
    const float* __restrict__ x, bf16_t* __restrict__ Q, bf16_t* __restrict__ K, bf16_t* __restrict__ V)
{
    int idx = blockIdx.x * 256 + threadIdx.x;  // < 16*768
    int c = idx % NC;
    int b = idx / NC;
    float xv = x[(size_t)b * NT * NC + c];
    int h = c >> 6, dk = c & 63;
    size_t base = ((size_t)(b * NH + h) * TP + 0) * DH + dk;
    Q[base] = (bf16_t)(xv * QK_SCALE);
    K[base] = (bf16_t)xv;
    V[base] = (bf16_t)xv;
}

// ---------------- V transpose: [bh][t][64] -> [bh][64][t] ----------------
__global__ __launch_bounds__(256) void transpose_v(
    const bf16_t* __restrict__ V, bf16_t* __restrict__ Vt)
{
    __shared__ bf16_t tile[64][65];
    int bh = blockIdx.y;
    int t0 = blockIdx.x * 64;
    for (int i = threadIdx.x; i < 64 * 64; i += 256) {
        int tt = i >> 6, dk = i & 63;
        int t = t0 + tt;
        tile[tt][dk] = (t < TP) ? V[((size_t)bh * TP + t) * DH + dk] : (bf16_t)0.f;
    }
    __syncthreads();
    for (int i = threadIdx.x; i < 64 * 64; i += 256) {
        int dk = i >> 6, tt = i & 63;
        int t = t0 + tt;
        if (t < TP) Vt[((size_t)bh * DH + dk) * TP + t] = tile[tt][dk];
    }
}

// ---------------- flash attention: 1 wave = 16 Q rows of one (b,h) ----------------
__global__ __launch_bounds__(64) void attn_kernel(
    const bf16_t* __restrict__ Q, const bf16_t* __restrict__ K,
    const bf16_t* __restrict__ Vt, bf16_t* __restrict__ Oa)
{
    int wid = blockIdx.x;          // 192*66
    int qt = wid % 66;
    int bh = wid / 66;
    int b = bh / NH, h = bh % NH;
    int lane = threadIdx.x;
    int cl = lane & 15;            // col within 16-tile
    int gr = lane >> 4;            // group 0..3

    const bf16_t* Qb = Q + ((size_t)bh * TP + qt * 16) * DH;
    const bf16_t* Kb = K + (size_t)bh * TP * DH;
    const bf16_t* Vb = Vt + (size_t)bh * DH * TP;

    // Q fragments for 2 k-steps (K-dim = 64)
    bf16x8 qf0 = *(const bf16x8*)(Qb + cl * DH + gr * 8);
    bf16x8 qf1 = *(const bf16x8*)(Qb + cl * DH + 32 + gr * 8);

    f32x4 o0 = {0.f, 0.f, 0.f, 0.f}, o1 = o0, o2 = o0, o3 = o0;
    float mrow[4] = {-1e30f, -1e30f, -1e30f, -1e30f};
    float lrow[4] = {0.f, 0.f, 0.f, 0.f};

    __shared__ alignas(16) bf16_t pl[16][32];

    for (int kt = 0; kt < 33; ++kt) {
        int t0 = kt * 32;
        f32x4 s0 = {0.f, 0.f, 0.f, 0.f}, s1 = s0;
        const bf16_t* K0 = Kb + (size_t)(t0 + cl) * DH;
        bf16x8 kf;
        kf = *(const bf16x8*)(K0 + gr * 8);
        s0 = __builtin_amdgcn_mfma_f32_16x16x32_bf16(qf0, kf, s0, 0, 0, 0);
        kf = *(const bf16x8*)(K0 + 32 + gr * 8);
        s0 = __builtin_amdgcn_mfma_f32_16x16x32_bf16(qf1, kf, s0, 0, 0, 0);
        kf = *(const bf16x8*)(K0 + 16 * DH + gr * 8);
        s1 = __builtin_amdgcn_mfma_f32_16x16x32_bf16(qf0, kf, s1, 0, 0, 0);
        kf = *(const bf16x8*)(K0 + 16 * DH + 32 + gr * 8);
        s1 = __builtin_amdgcn_mfma_f32_16x16x32_bf16(qf1, kf, s1, 0, 0, 0);

        bool msk0 = (t0 + cl) >= NT;        // mask padded key columns
        bool msk1 = (t0 + 16 + cl) >= NT;
#pragma unroll
        for (int j = 0; j < 4; ++j) {
            float a = msk0 ? -1e30f : s0[j];
            float bb = msk1 ? -1e30f : s1[j];
            float mx = fmaxf(a, bb);
            mx = fmaxf(mx, __shfl_xor(mx, 1));
            mx = fmaxf(mx, __shfl_xor(mx, 2));
            mx = fmaxf(mx, __shfl_xor(mx, 4));
            mx = fmaxf(mx, __shfl_xor(mx, 8));
            float mn = fmaxf(mrow[j], mx);
            float alpha = __expf(mrow[j] - mn);
            mrow[j] = mn;
            float p0 = __expf(a - mn);
            float p1 = __expf(bb - mn);
            s0[j] = p0;
            s1[j] = p1;
            float rs = p0 + p1;
            rs += __shfl_xor(rs, 1);
            rs += __shfl_xor(rs, 2);
            rs += __shfl_xor(rs, 4);
            rs += __shfl_xor(rs, 8);
            lrow[j] = lrow[j] * alpha + rs;
            o0[j] *= alpha; o1[j] *= alpha; o2[j] *= alpha; o3[j] *= alpha;
        }
        // P tile (16x32) through LDS to get A-fragment layout
#pragma unroll
        for (int j = 0; j < 4; ++j) {
            pl[gr * 4 + j][cl] = (bf16_t)s0[j];
            pl[gr * 4 + j][16 + cl] = (bf16_t)s1[j];
        }
        __syncthreads();
        bf16x8 pa = *(const bf16x8*)(&pl[cl][gr * 8]);
        const bf16_t* V0 = Vb + t0 + gr * 8;
        bf16x8 vf;
        vf = *(const bf16x8*)(V0 + (size_t)(0 * 16 + cl) * TP);
        o0 = __builtin_amdgcn_mfma_f32_16x16x32_bf16(pa, vf, o0, 0, 0, 0);
        vf = *(const bf16x8*)(V0 + (size_t)(1 * 16 + cl) * TP);
        o1 = __builtin_amdgcn_mfma_f32_16x16x32_bf16(pa, vf, o1, 0, 0, 0);
        vf = *(const bf16x8*)(V0 + (size_t)(2 * 16 + cl) * TP);
        o2 = __builtin_amdgcn_mfma_f32_16x16x32_bf16(pa, vf, o2, 0, 0, 0);
        vf = *(const bf16x8*)(V0 + (size_t)(3 * 16 + cl) * TP);
        o3 = __builtin_amdgcn_mfma_f32_16x16x32_bf16(pa, vf, o3, 0, 0, 0);
        __syncthreads();
    }

    int tr0 = qt * 16;
#pragma unroll
    for (int j = 0; j < 4; ++j) {
        int t = tr0 + gr * 4 + j;
        if (t < NT) {
            float inv = 1.0f / lrow[j];
            size_t row = ((size_t)b * NT + t) * NC + h * DH;
            Oa[row + 0 * 16 + cl] = (bf16_t)(o0[j] * inv);
            Oa[row + 1 * 16 + cl] = (bf16_t)(o1[j] * inv);
            Oa[row + 2 * 16 + cl] = (bf16_t)(o2[j] * inv);
            Oa[row + 3 * 16 + cl] = (bf16_t)(o3[j] * inv);
        }
    }
}

// ---------------- W -> bf16 ----------------
__global__ __launch_bounds__(256) void conv_w(const float* __restrict__ W, bf16_t* __restrict__ Wb)
{
    int i = blockIdx.x * 256 + threadIdx.x;
    if (i < NC * NC) Wb[i] = (bf16_t)W[i];
}

// ---------------- projection GEMM: out[n][j] = sum_c Oa[n][c]*W[j][c] + bias[j] ----------------
__global__ __launch_bounds__(64) void proj_gemm(
    const bf16_t* __restrict__ Oa, const bf16_t* __restrict__ Wb,
    const float* __restrict__ bias, float* __restrict__ out)
{
    int wid = blockIdx.x;          // 1025 * 12
    int nt = wid % 12;             // 64-col tile
    int mt = wid / 12;             // 16-row tile
    int lane = threadIdx.x;
    int cl = lane & 15, gr = lane >> 4;

    const bf16_t* A = Oa + ((size_t)mt * 16 + cl) * NC + gr * 8;
    const bf16_t* Bp = Wb + ((size_t)(nt * 64 + cl)) * NC + gr * 8;
    f32x4 a0 = {0.f, 0.f, 0.f, 0.f}, a1 = a0, a2 = a0, a3 = a0;
#pragma unroll 4
    for (int ks = 0; ks < 24; ++ks) {
        bf16x8 af = *(const bf16x8*)(A + ks * 32);
        bf16x8 b0 = *(const bf16x8*)(Bp + 0 * 16 * NC + ks * 32);
        bf16x8 b1 = *(const bf16x8*)(Bp + 1 * 16 * NC + ks * 32);
        bf16x8 b2 = *(const bf16x8*)(Bp + 2 * 16 * NC + ks * 32);
        bf16x8 b3 = *(const bf16x8*)(Bp + 3 * 16 * NC + ks * 32);
        a0 = __builtin_amdgcn_mfma_f32_16x16x32_bf16(af, b0, a0, 0, 0, 0);
        a1 = __builtin_amdgcn_mfma_f32_16x16x32_bf16(af, b1, a1, 0, 0, 0);
        a2 = __builtin_amdgcn_mfma_f32_16x16x32_bf16(af, b2, a2, 0, 0, 0);
        a3 = __builtin_amdgcn_mfma_f32_16x16x32_bf16(af, b3, a3, 0, 0, 0);
    }
#pragma unroll
    for (int j = 0; j < 4; ++j) {
        int col = nt * 64 + j * 16 + cl;
        float bv = bias[col];
        f32x4 acc = (j == 0) ? a0 : (j == 1) ? a1 : (j == 2) ? a2 : a3;
#pragma unroll
        for (int jj = 0; jj < 4; ++jj) {
            int r = mt * 16 + gr * 4 + jj;
            out[(size_t)r * NC + col] = acc[jj] + bv;
        }
    }
}

extern "C" void kernel_launch(void* const* d_in, const int* in_sizes, int n_in,
                              void* d_out, int out_size, void* d_ws, size_t ws_size,
                              hipStream_t stream)
{
    const float* x = (const float*)d_in[0];
    // d_in[1]=h, d_in[2]=w (ints, fixed 32)
    const float* wq = (const float*)d_in[3];
    const float* gq = (const float*)d_in[4];
    const float* bq = (const float*)d_in[5];
    const float* mq = (const float*)d_in[6];
    const float* vq = (const float*)d_in[7];
    const float* wk = (const float*)d_in[8];
    const float* gk = (const float*)d_in[9];
    const float* bk = (const float*)d_in[10];
    const float* mk = (const float*)d_in[11];
    const float* vk = (const float*)d_in[12];
    const float* wv = (const float*)d_in[13];
    const float* gv = (const float*)d_in[14];
    const float* bv = (const float*)d_in[15];
    const float* mv = (const float*)d_in[16];
    const float* vv = (const float*)d_in[17];
    const float* pw = (const float*)d_in[18];
    const float* pb = (const float*)d_in[19];
    float* out = (float*)d_out;

    const size_t QKV_ELEMS = (size_t)NB * NH * TP * DH;   // 12,976,128
    bf16_t* ws = (bf16_t*)d_ws;
    bf16_t* Q  = ws;
    bf16_t* K  = ws + QKV_ELEMS;
    bf16_t* V  = ws + 2 * QKV_ELEMS;
    bf16_t* Vt = ws + 3 * QKV_ELEMS;
    bf16_t* Oa = ws + 4 * QKV_ELEMS;                      // 16400*768 bf16
    bf16_t* Wb = Oa + (size_t)NB * NT * NC;

    conv_w<<<(NC * NC + 255) / 256, 256, 0, stream>>>(pw, Wb);
    qkv_conv<<<dim3(8, 3, NB), 256, 0, stream>>>(
        x, wq, gq, bq, mq, vq, wk, gk, bk, mk, vk, wv, gv, bv, mv, vv, Q, K, V);
    cls_fill<<<(NB * NC) / 256, 256, 0, stream>>>(x, Q, K, V);
    transpose_v<<<dim3(17, NB * NH), 256, 0, stream>>>(V, Vt);
    attn_kernel<<<NB * NH * 66, 64, 0, stream>>>(Q, K, Vt, Oa);
    proj_gemm<<<1025 * 12, 64, 0, stream>>>(Oa, Wb, pb, out);
}